// Round 7
// baseline (192.504 us; speedup 1.0000x reference)
//
#include <hip/hip_runtime.h>
#include <math.h>

// Problem shape (from reference setup_inputs): B=4096, D=2048, C=1000, N=C+B=5096.
#define D_DIM 2048
// |approx_logit - exact_logit| bound: fp16-MFMA dot (~0.013) + 4x f16 partial
// roundings (~0.008). Candidate containment needs GAP_TAU >= true bound.
#define GAP_TAU 0.03f
#define SPLITK 4
#define MAXLIST 1024

typedef _Float16 f16;
typedef f16 f16x8 __attribute__((ext_vector_type(8)));
typedef f16 f16x4 __attribute__((ext_vector_type(4)));
typedef float f32x4 __attribute__((ext_vector_type(4)));
typedef float f32x16 __attribute__((ext_vector_type(16)));

__device__ __forceinline__ const float* support_row(int i, const float* __restrict__ W,
                                                    const float* __restrict__ z, int C) {
  return (i < C) ? (W + (size_t)i * D_DIM) : (z + (size_t)(i - C) * D_DIM);
}

// async global->LDS, 16B per lane. LDS dest = wave-uniform base + lane*16.
__device__ __forceinline__ void async_ld16(const f16* g, f16* l) {
  __builtin_amdgcn_global_load_lds((const __attribute__((address_space(1))) void*)g,
                                   (__attribute__((address_space(3))) void*)l, 16, 0, 0);
}

// ---------------------------------------------------------------------------
// prep: suph[i][:] = f16(support_row(i)) (zeros for pad rows); norms[i] = ||row||.
// One wave per row (4 rows/block), shuffle-only reduction.
// Also zeroes cls_cnt[0..C) and *repCnt (consumed after row_stats_fast).
// ---------------------------------------------------------------------------
__global__ __launch_bounds__(256) void prep_kernel(const float* __restrict__ z,
                                                   const float* __restrict__ W,
                                                   int C, int Nsup,
                                                   f16* __restrict__ suph,
                                                   float* __restrict__ norms,
                                                   int* __restrict__ cls_cnt,
                                                   int* __restrict__ repCnt) {
  if (blockIdx.x * 256 <= (unsigned)C) {
    const int gi = blockIdx.x * 256 + threadIdx.x;
    if (gi < C) cls_cnt[gi] = 0;
    if (gi == C) *repCnt = 0;
  }
  const int wave = threadIdx.x >> 6;
  const int lane = threadIdx.x & 63;
  const int i = blockIdx.x * 4 + wave;
  f16* dst = suph + (size_t)i * D_DIM;
  if (i >= Nsup) {
    f16x8 zz = {0, 0, 0, 0, 0, 0, 0, 0};
#pragma unroll
    for (int p = 0; p < 4; p++) *(f16x8*)(dst + p * 512 + lane * 8) = zz;
    return;
  }
  const float* src = support_row(i, W, z, C);
  float ss = 0.f;
#pragma unroll
  for (int p = 0; p < 4; p++) {
    const int off = p * 512 + lane * 8;
    const float4 a = *(const float4*)(src + off);
    const float4 b = *(const float4*)(src + off + 4);
    f16x8 v;
    v[0] = (f16)a.x; v[1] = (f16)a.y; v[2] = (f16)a.z; v[3] = (f16)a.w;
    v[4] = (f16)b.x; v[5] = (f16)b.y; v[6] = (f16)b.z; v[7] = (f16)b.w;
    *(f16x8*)(dst + off) = v;
    ss = fmaf(a.x, a.x, ss); ss = fmaf(a.y, a.y, ss);
    ss = fmaf(a.z, a.z, ss); ss = fmaf(a.w, a.w, ss);
    ss = fmaf(b.x, b.x, ss); ss = fmaf(b.y, b.y, ss);
    ss = fmaf(b.z, b.z, ss); ss = fmaf(b.w, b.w, ss);
  }
#pragma unroll
  for (int s = 1; s < 64; s <<= 1) ss += __shfl_xor(ss, s);
  if (lane == 0) norms[i] = sqrtf(ss);
}

// ---------------------------------------------------------------------------
// fp16 MFMA GEMM, split-K=4, f16 partials, BK=64, XCD-pinned work mapping.
// 128x128 tile, 256 thr = 4 waves (2x2), wave = 64x64 = 2x2 MFMA 32x32x16,
// 4 k-steps of K=16 per BK=64 iter (8 iters at Ks=512). LDS 32 KB single
// buffer -> 4 blocks/CU resident (VGPR 88 caps 4 waves/SIMD; LDS allows 5).
// Round-7 rationale (round-6 PMC): all pipes low + Occupancy 12.9% at grid
// 640 = latency/occupancy-bound. Split-K=4 -> grid 1280/1024 (exact CU
// multiples) doubles resident waves; cross-block overlap (m114) hides the
// stage->barrier chain. Interior verbatim round-3 (proven, same speed as dbuf).
// Swizzle: physical chunk p = g ^ (row&7); quarter-wave 2-way alias only
// (free, m136). C/D 32x32: col=lane&31, row=(reg&3)+8*(reg>>2)+4*(lane>>5).
// ---------------------------------------------------------------------------
#define TM 128
#define TN 128
#define BK 64

__global__ __launch_bounds__(256) void gemm_f16(const f16* __restrict__ A,
                                                const f16* __restrict__ B,
                                                f16* __restrict__ P,
                                                int K, int Ks, long partStride, int ldc,
                                                int txPerXcd) {
  __shared__ __align__(16) f16 As[TM * BK];  // 16 KB
  __shared__ __align__(16) f16 Bs[TN * BK];  // 16 KB

  const int l = blockIdx.x;
  const int xcd = l & 7;
  const int slot = l >> 3;
  const int tx = xcd + 8 * (slot % txPerXcd);
  const int rest = slot / txPerXcd;        // 0..31 (8 ty * 4 kz)
  const int ty = rest & 7;
  const int kz = rest >> 3;                // 0..3
  const int row0 = tx * TM;
  const int col0 = ty * TN;
  const int kbase = kz * Ks;

  const int tid = threadIdx.x;
  const int wave = tid >> 6;
  const int lane = tid & 63;
  const int lr32 = lane & 31;    // row within 32-block (A) / col (B, C/D)
  const int half = lane >> 5;    // k-chunk half selector
  const int wr = (wave >> 1) * 64;
  const int wc = (wave & 1) * 64;

  // staging: 1024 16B-chunks per tile -> 4 instr/thread for A, 4 for B.
  // chunk id i = (row<<3)|p; source global chunk g = p ^ (row&7).
  const f16* ag[4];
  const f16* bg[4];
  f16* al[4];
  f16* bl[4];
#pragma unroll
  for (int s = 0; s < 4; s++) {
    const int i = (wave * 4 + s) * 64 + lane;   // == LDS chunk id (staging contract)
    const int row = i >> 3;
    const int cg = (i & 7) ^ (row & 7);
    ag[s] = A + (size_t)(row0 + row) * K + kbase + cg * 8;
    bg[s] = B + (size_t)(col0 + row) * K + kbase + cg * 8;
    al[s] = As + (wave * 4 + s) * 512;
    bl[s] = Bs + (wave * 4 + s) * 512;
  }

  // fragment offsets: for k-step s (K=16), lane reads global chunk
  // (s*2 + half) of row r at physical chunk ((s*2+half) ^ (r&7)).
  int aoff[2][4], boff[2][4];
#pragma unroll
  for (int b = 0; b < 2; b++) {
#pragma unroll
    for (int s = 0; s < 4; s++) {
      const int ra = wr + b * 32 + lr32;
      aoff[b][s] = ra * 64 + (((s * 2 + half) ^ (ra & 7)) << 3);
      const int rb = wc + b * 32 + lr32;
      boff[b][s] = rb * 64 + (((s * 2 + half) ^ (rb & 7)) << 3);
    }
  }

  f32x16 acc[2][2];
#pragma unroll
  for (int i = 0; i < 2; i++)
#pragma unroll
    for (int j = 0; j < 2; j++)
#pragma unroll
      for (int r = 0; r < 16; r++) acc[i][j][r] = 0.f;

  for (int k0 = 0; k0 < Ks; k0 += BK) {
#pragma unroll
    for (int s = 0; s < 4; s++) {
      async_ld16(ag[s] + k0, al[s]);
      async_ld16(bg[s] + k0, bl[s]);
    }
    __syncthreads();

#pragma unroll
    for (int s = 0; s < 4; s++) {
      f16x8 af[2], bf[2];
      af[0] = *(const f16x8*)(As + aoff[0][s]);
      af[1] = *(const f16x8*)(As + aoff[1][s]);
      bf[0] = *(const f16x8*)(Bs + boff[0][s]);
      bf[1] = *(const f16x8*)(Bs + boff[1][s]);
      acc[0][0] = __builtin_amdgcn_mfma_f32_32x32x16_f16(af[0], bf[0], acc[0][0], 0, 0, 0);
      acc[0][1] = __builtin_amdgcn_mfma_f32_32x32x16_f16(af[0], bf[1], acc[0][1], 0, 0, 0);
      acc[1][0] = __builtin_amdgcn_mfma_f32_32x32x16_f16(af[1], bf[0], acc[1][0], 0, 0, 0);
      acc[1][1] = __builtin_amdgcn_mfma_f32_32x32x16_f16(af[1], bf[1], acc[1][1], 0, 0, 0);
    }
    __syncthreads();
  }

  f16* out = P + (size_t)kz * partStride;
#pragma unroll
  for (int bi = 0; bi < 2; bi++)
#pragma unroll
    for (int reg = 0; reg < 16; reg++) {
      const int r = row0 + wr + bi * 32 + (reg & 3) + ((reg >> 2) << 3) + (half << 2);
#pragma unroll
      for (int bj = 0; bj < 2; bj++) {
        const int c = col0 + wc + bj * 32 + lr32;
        out[(size_t)r * ldc + c] = (f16)acc[bi][bj][reg];
      }
    }
}

// ---------------------------------------------------------------------------
// row_stats_fast: ONE WAVE per row, zero barriers. Lane owns 16 cols
// (lane*8..+7 and 512+lane*8..+7), coalesced f16x8 loads of all SPLITK
// partials. Top-2/argmax + entropy via shfl_xor butterflies. Ambiguous rows
// go to a repair list; others bucket into per-class lists.
// ---------------------------------------------------------------------------
__global__ __launch_bounds__(256) void row_stats_fast(
    const f16* __restrict__ P, long partStride, int ldp, int Cc, int Nsup,
    float* __restrict__ ent, int* __restrict__ repCnt, int* __restrict__ repRows,
    int* __restrict__ cls_cnt, int* __restrict__ cls_idx) {
  const int wave = threadIdx.x >> 6;
  const int lane = threadIdx.x & 63;
  const int r = blockIdx.x * 4 + wave;
  if (r >= Nsup) return;

  const f16* base = P + (size_t)r * ldp + lane * 8;
  float v[16];
#pragma unroll
  for (int k = 0; k < 16; k++) v[k] = 0.f;
#pragma unroll
  for (int kz = 0; kz < SPLITK; kz++) {
    const f16* b2 = base + (size_t)kz * partStride;
    const f16x8 p0 = *(const f16x8*)(b2);
    const f16x8 p1 = *(const f16x8*)(b2 + 512);
#pragma unroll
    for (int k = 0; k < 8; k++) { v[k] += (float)p0[k]; v[8 + k] += (float)p1[k]; }
  }

  const int cbase = lane * 8;
#pragma unroll
  for (int k = 0; k < 16; k++) {
    const int col = (k < 8) ? (cbase + k) : (512 + cbase + k - 8);
    if (col >= Cc) v[k] = -3.0e38f;
  }

  // per-lane top-2 (+ lowest argmax idx; ascending col order within lane)
  float m1 = -3.0e38f, m2 = -3.0e38f;
  int i1 = 0x7fffffff;
#pragma unroll
  for (int k = 0; k < 16; k++) {
    const int col = (k < 8) ? (cbase + k) : (512 + cbase + k - 8);
    const float x = v[k];
    if (x > m1) { m2 = m1; m1 = x; i1 = col; }
    else if (x > m2) { m2 = x; }   // x==m1 lands here -> m2=m1 (gap 0)
  }
  // butterfly merge: all lanes converge to global (m1, m2, lowest i1)
#pragma unroll
  for (int s = 1; s < 64; s <<= 1) {
    const float om1 = __shfl_xor(m1, s);
    const float om2 = __shfl_xor(m2, s);
    const int oi1 = __shfl_xor(i1, s);
    if (om1 > m1) { m2 = fmaxf(m1, om2); m1 = om1; i1 = oi1; }
    else if (om1 < m1) { m2 = fmaxf(m2, om1); }
    else { i1 = min(i1, oi1); m2 = m1; }
  }

  // entropy rel. m1 (consumed only if a class exceeds K members)
  float s1 = 0.f, s2 = 0.f;
#pragma unroll
  for (int k = 0; k < 16; k++) {
    const int col = (k < 8) ? (cbase + k) : (512 + cbase + k - 8);
    if (col < Cc) {
      const float d = v[k] - m1;
      const float e = __expf(d);
      s1 += e;
      s2 = fmaf(d, e, s2);
    }
  }
#pragma unroll
  for (int s = 1; s < 64; s <<= 1) {
    s1 += __shfl_xor(s1, s);
    s2 += __shfl_xor(s2, s);
  }

  if (lane == 0) {
    ent[r] = logf(s1) - s2 / s1;
    if (m1 - m2 <= 2.0f * GAP_TAU) {
      const int p = atomicAdd(repCnt, 1);
      if (p < Nsup) repRows[p] = r;
    } else {
      const int p = atomicAdd(&cls_cnt[i1], 1);
      if (p < MAXLIST) cls_idx[(size_t)i1 * MAXLIST + p] = r;
    }
  }
}

// ---------------------------------------------------------------------------
// repair: one block per ambiguous row (strided over runtime count). Recomputes
// M1/M2 (exact comparisons -> same values as fast path), then the VERBATIM old
// candidate collection + exact fp32 block-dot code -> yhat unchanged.
// Buckets the resolved class.
// ---------------------------------------------------------------------------
__global__ __launch_bounds__(256) void repair_kernel(
    const f16* __restrict__ P, long partStride, int ldp, int Cc,
    const float* __restrict__ z, const float* __restrict__ W,
    const int* __restrict__ repCnt, const int* __restrict__ repRows,
    int* __restrict__ cls_cnt, int* __restrict__ cls_idx) {
  const int t = threadIdx.x;
  const int wave = t >> 6;
  const int lane = t & 63;
  __shared__ float sm1[4], sm2[4];
  __shared__ float bc[2];
  __shared__ int cand[64];
  __shared__ int ncand;
  __shared__ float red[256];
  const int nrep = *repCnt;

  for (int q = blockIdx.x; q < nrep; q += gridDim.x) {
    const int r = repRows[q];
    const int c0 = t * 4;
    float v[4] = {0.f, 0.f, 0.f, 0.f};
#pragma unroll
    for (int kz = 0; kz < SPLITK; kz++) {
      const f16x4 p = *(const f16x4*)(P + (size_t)kz * partStride + (size_t)r * ldp + c0);
#pragma unroll
      for (int k = 0; k < 4; k++) v[k] += (float)p[k];
    }
#pragma unroll
    for (int k = 0; k < 4; k++)
      if (c0 + k >= Cc) v[k] = -3.0e38f;

    // top-2 values only (indices resolved by exact dots below)
    float m1 = -3.0e38f, m2 = -3.0e38f;
#pragma unroll
    for (int k = 0; k < 4; k++) {
      const float x = v[k];
      if (x > m1) { m2 = m1; m1 = x; }
      else if (x > m2) { m2 = x; }
    }
#pragma unroll
    for (int s = 1; s < 64; s <<= 1) {
      const float om1 = __shfl_xor(m1, s);
      const float om2 = __shfl_xor(m2, s);
      if (om1 > m1) { m2 = fmaxf(m1, om2); m1 = om1; }
      else if (om1 < m1) { m2 = fmaxf(m2, om1); }
      else { m2 = m1; }
    }
    if (lane == 0) { sm1[wave] = m1; sm2[wave] = m2; }
    __syncthreads();
    if (t == 0) {
      float M1 = sm1[0], M2 = sm2[0];
#pragma unroll
      for (int w = 1; w < 4; w++) {
        const float o1 = sm1[w], o2 = sm2[w];
        if (o1 > M1) { M2 = fmaxf(M1, o2); M1 = o1; }
        else if (o1 < M1) { M2 = fmaxf(M2, o1); }
        else { M2 = M1; }
      }
      bc[0] = M1; bc[1] = M2;
      ncand = 0;
    }
    __syncthreads();
    const float M1 = bc[0];
    const float thresh = M1 - 2.0f * GAP_TAU;
#pragma unroll
    for (int k = 0; k < 4; k++) {
      if (c0 + k < Cc && v[k] >= thresh) {
        const int p = atomicAdd(&ncand, 1);
        if (p < 64) cand[p] = c0 + k;
      }
    }
    __syncthreads();
    const bool overflow = (ncand > 64);
    const int nc = overflow ? Cc : ncand;
    const float* srow = support_row(r, W, z, Cc);
    float best = -3.0e38f;
    int bi = 0x7fffffff;
    for (int j = 0; j < nc; j++) {
      const int c = overflow ? j : cand[j];
      const float* wrow = W + (size_t)c * D_DIM;
      float s = 0.f;
      for (int d = t; d < D_DIM; d += 256) s = fmaf(srow[d], wrow[d], s);
      red[t] = s;
      __syncthreads();
      for (int k = 128; k > 0; k >>= 1) {
        if (t < k) red[t] += red[t + k];
        __syncthreads();
      }
      const float val = red[0];
      __syncthreads();
      if (val > best || (val == best && c < bi)) { best = val; bi = c; }
    }
    if (t == 0) {
      const int p = atomicAdd(&cls_cnt[bi], 1);
      if (p < MAXLIST) cls_idx[(size_t)bi * MAXLIST + p] = r;
    }
    __syncthreads();   // shared reuse across q iterations
  }
}

// ---------------------------------------------------------------------------
// accum: per class — read pre-bucketed member list, top-K by entropy if
// count > K (never in practice: mean ~5, K=100), sum normalized rows,
// column-normalize, write f16 weights row. Pad classes write zeros.
// ---------------------------------------------------------------------------
__global__ __launch_bounds__(256) void accum_kernel(
    const float* __restrict__ z, const float* __restrict__ W,
    int C, int Nsup,
    const int* __restrict__ cls_cnt, const int* __restrict__ cls_idx,
    const float* __restrict__ ent, const float* __restrict__ norms,
    const int* __restrict__ Kp, f16* __restrict__ wh) {
  const int c = blockIdx.x;
  const int t = threadIdx.x;
  f16* dst = wh + (size_t)c * D_DIM + t * 8;
  if (c >= C) {
    f16x8 zz = {0, 0, 0, 0, 0, 0, 0, 0};
    *(f16x8*)dst = zz;
    return;
  }

  __shared__ int slist[MAXLIST];
  __shared__ unsigned char sel[MAXLIST];
  __shared__ float red[256];
  const int cnt = cls_cnt[c];
  const int n = min(cnt, MAXLIST);
  const int* list = cls_idx + (size_t)c * MAXLIST;
  for (int j = t; j < n; j += 256) slist[j] = list[j];
  __syncthreads();
  const int K = *Kp;
  const bool all = (cnt <= K);
  if (!all) {
    for (int j = t; j < n; j += 256) {
      const int si = slist[j];
      const float ei = ent[si];
      int rank = 0;
      for (int l = 0; l < n; l++) {
        const int sl = slist[l];
        const float el = ent[sl];
        rank += (el < ei || (el == ei && sl < si)) ? 1 : 0;
      }
      sel[j] = (rank < K) ? 1 : 0;
    }
    __syncthreads();
  }

  float a[8];
#pragma unroll
  for (int q = 0; q < 8; q++) a[q] = 0.f;
  for (int j = 0; j < n; j++) {
    if (!all && !sel[j]) continue;
    const int si = slist[j];
    const float* row = support_row(si, W, z, C) + t * 8;
    const float inv = 1.0f / fmaxf(norms[si], 1e-12f);
    const float4 p0 = *(const float4*)row;
    const float4 p1 = *(const float4*)(row + 4);
    a[0] = fmaf(p0.x, inv, a[0]); a[1] = fmaf(p0.y, inv, a[1]);
    a[2] = fmaf(p0.z, inv, a[2]); a[3] = fmaf(p0.w, inv, a[3]);
    a[4] = fmaf(p1.x, inv, a[4]); a[5] = fmaf(p1.y, inv, a[5]);
    a[6] = fmaf(p1.z, inv, a[6]); a[7] = fmaf(p1.w, inv, a[7]);
  }

  float ss = 0.f;
#pragma unroll
  for (int q = 0; q < 8; q++) ss = fmaf(a[q], a[q], ss);
  red[t] = ss;
  __syncthreads();
  for (int k = 128; k > 0; k >>= 1) {
    if (t < k) red[t] += red[t + k];
    __syncthreads();
  }
  const float invn = 1.0f / fmaxf(sqrtf(red[0]), 1e-12f);
  f16x8 o;
#pragma unroll
  for (int q = 0; q < 8; q++) o[q] = (f16)(a[q] * invn);
  *(f16x8*)dst = o;
}

// ---------------------------------------------------------------------------
// reduce_out: out[r][c] = sum of SPLITK f16 partials, c < Ncols. Two rows per
// block; thread owns 8 cols (f16x8 loads, 2x float4 store).
// ---------------------------------------------------------------------------
__global__ __launch_bounds__(256) void reduce_out(const f16* __restrict__ Q,
                                                  long partStride, int ldq,
                                                  float* __restrict__ out, int Ncols) {
  const int r = blockIdx.x * 2 + (threadIdx.x >> 7);
  const int c0 = (threadIdx.x & 127) * 8;
  const f16* base = Q + (size_t)r * ldq + c0;
  float v[8];
#pragma unroll
  for (int k = 0; k < 8; k++) v[k] = 0.f;
#pragma unroll
  for (int kz = 0; kz < SPLITK; kz++) {
    const f16x8 p = *(const f16x8*)(base + (size_t)kz * partStride);
#pragma unroll
    for (int k = 0; k < 8; k++) v[k] += (float)p[k];
  }
  float* o = out + (size_t)r * Ncols + c0;
  if (c0 + 8 <= Ncols) {
    *(float4*)(o) = make_float4(v[0], v[1], v[2], v[3]);
    *(float4*)(o + 4) = make_float4(v[4], v[5], v[6], v[7]);
  } else {
#pragma unroll
    for (int k = 0; k < 8; k++)
      if (c0 + k < Ncols) o[k] = v[k];
  }
}

// ---------------------------------------------------------------------------
// Launch
// ---------------------------------------------------------------------------
extern "C" void kernel_launch(void* const* d_in, const int* in_sizes, int n_in,
                              void* d_out, int out_size, void* d_ws, size_t ws_size,
                              hipStream_t stream) {
  const float* z = (const float*)d_in[0];
  const float* W = (const float*)d_in[1];
  const int* Kp = (const int*)d_in[2];

  const int D = D_DIM;
  const int B = in_sizes[0] / D;   // 4096
  const int C = in_sizes[1] / D;   // 1000
  const int Nsup = C + B;          // 5096
  const int Mpad = (Nsup + TM - 1) / TM * TM;  // 5120
  const int Npad = (C + TN - 1) / TN * TN;     // 1024

  char* ws = (char*)d_ws;
  size_t off = 0;
  auto alloc = [&](size_t bytes) -> void* {
    void* p = ws + off;
    off += (bytes + 255) & ~(size_t)255;
    return p;
  };

  const long pStride1 = (long)Mpad * Npad;   // f16 elems per partial (gemm1)
  const long pStride2 = (long)B * Npad;      // f16 elems per partial (gemm2)

  f16*   suph   = (f16*)alloc((size_t)Mpad * D * sizeof(f16));            // ~21.0 MB
  f16*   wh     = (f16*)alloc((size_t)Npad * D * sizeof(f16));            // ~4.2 MB
  f16*   P      = (f16*)alloc((size_t)SPLITK * pStride1 * sizeof(f16));   // ~41.9 MB
  float* ent    = (float*)alloc((size_t)Nsup * sizeof(float));
  float* norms  = (float*)alloc((size_t)Nsup * sizeof(float));
  int*   cls_cnt = (int*)alloc((size_t)C * sizeof(int));
  int*   cls_idx = (int*)alloc((size_t)C * MAXLIST * sizeof(int));        // ~4.1 MB
  int*   repCnt = (int*)alloc(sizeof(int));
  int*   repRows = (int*)alloc((size_t)Nsup * sizeof(int));
  f16*   Q      = P;  // reuse: P fully consumed by row_stats/repair before gemm2
  (void)ws_size;

  // 1) f16 support matrix (padded) + norms; zero class/repair counters
  prep_kernel<<<Mpad / 4, 256, 0, stream>>>(z, W, C, Nsup, suph, norms, cls_cnt, repCnt);

  // 2) logit partials: P[kz] = f16(supports @ W^T over K-quarter kz)
  //    1D grid 1280 = 8 xcd * 5 txPerXcd * 8 ty * 4 kz = 5 x 256 CUs exactly
  {
    const int txPerXcd = (Mpad / TM) / 8;   // 5
    gemm_f16<<<1280, 256, 0, stream>>>(suph, suph, P, D, D / SPLITK, pStride1, Npad,
                                       txPerXcd);
  }

  // 3) wave-per-row split-K merge + argmax/entropy; ambiguous -> repair list,
  //    resolved -> class buckets
  row_stats_fast<<<(Nsup + 3) / 4, 256, 0, stream>>>(P, pStride1, Npad, C, Nsup,
                                                     ent, repCnt, repRows,
                                                     cls_cnt, cls_idx);

  // 4) exact fp32 repair of ambiguous rows
  repair_kernel<<<1024, 256, 0, stream>>>(P, pStride1, Npad, C, z, W,
                                          repCnt, repRows, cls_cnt, cls_idx);

  // 5) per-class gather/select/accumulate/normalize -> wh[Npad, D] f16
  accum_kernel<<<Npad, 256, 0, stream>>>(z, W, C, Nsup, cls_cnt, cls_idx,
                                         ent, norms, Kp, wh);

  // 6) output partials: Q[kz] = f16(z @ weights^T over K-quarter kz)
  //    1D grid 1024 = 8 xcd * 4 txPerXcd * 8 ty * 4 kz = 4 x 256 CUs exactly
  {
    const int txPerXcd = (B / TM) / 8;      // 4
    gemm_f16<<<1024, 256, 0, stream>>>(suph + (size_t)C * D, wh, Q, D, D / SPLITK,
                                       pStride2, Npad, txPerXcd);
  }

  // 7) out = sum of SPLITK f16 partials (valid C cols only)
  reduce_out<<<B / 2, 256, 0, stream>>>(Q, pStride2, Npad, (float*)d_out, C);
}

// Round 8
// 179.461 us; speedup vs baseline: 1.0727x; 1.0727x over previous
//
#include <hip/hip_runtime.h>
#include <math.h>

// Problem shape (from reference setup_inputs): B=4096, D=2048, C=1000, N=C+B=5096.
#define D_DIM 2048
// |approx_logit - exact_logit| bound: fp16-MFMA dot (~0.013) + 2x f16 partial
// roundings (~0.004). Candidate containment needs GAP_TAU >= true bound.
#define GAP_TAU 0.03f
#define SPLITK 2
#define MAXLIST 1024

typedef _Float16 f16;
typedef f16 f16x8 __attribute__((ext_vector_type(8)));
typedef f16 f16x4 __attribute__((ext_vector_type(4)));
typedef float f32x4 __attribute__((ext_vector_type(4)));
typedef float f32x16 __attribute__((ext_vector_type(16)));

__device__ __forceinline__ const float* support_row(int i, const float* __restrict__ W,
                                                    const float* __restrict__ z, int C) {
  return (i < C) ? (W + (size_t)i * D_DIM) : (z + (size_t)(i - C) * D_DIM);
}

// async global->LDS, 16B per lane. LDS dest = wave-uniform base + lane*16.
__device__ __forceinline__ void async_ld16(const f16* g, f16* l) {
  __builtin_amdgcn_global_load_lds((const __attribute__((address_space(1))) void*)g,
                                   (__attribute__((address_space(3))) void*)l, 16, 0, 0);
}

// ---------------------------------------------------------------------------
// prep: suph[i][:] = f16(support_row(i)) (zeros for pad rows); norms[i] = ||row||.
// One wave per row (4 rows/block), shuffle-only reduction.
// Also zeroes cls_cnt[0..C) and *repCnt (consumed after row_stats_fast).
// ---------------------------------------------------------------------------
__global__ __launch_bounds__(256) void prep_kernel(const float* __restrict__ z,
                                                   const float* __restrict__ W,
                                                   int C, int Nsup,
                                                   f16* __restrict__ suph,
                                                   float* __restrict__ norms,
                                                   int* __restrict__ cls_cnt,
                                                   int* __restrict__ repCnt) {
  if (blockIdx.x * 256 <= (unsigned)C) {
    const int gi = blockIdx.x * 256 + threadIdx.x;
    if (gi < C) cls_cnt[gi] = 0;
    if (gi == C) *repCnt = 0;
  }
  const int wave = threadIdx.x >> 6;
  const int lane = threadIdx.x & 63;
  const int i = blockIdx.x * 4 + wave;
  f16* dst = suph + (size_t)i * D_DIM;
  if (i >= Nsup) {
    f16x8 zz = {0, 0, 0, 0, 0, 0, 0, 0};
#pragma unroll
    for (int p = 0; p < 4; p++) *(f16x8*)(dst + p * 512 + lane * 8) = zz;
    return;
  }
  const float* src = support_row(i, W, z, C);
  float ss = 0.f;
#pragma unroll
  for (int p = 0; p < 4; p++) {
    const int off = p * 512 + lane * 8;
    const float4 a = *(const float4*)(src + off);
    const float4 b = *(const float4*)(src + off + 4);
    f16x8 v;
    v[0] = (f16)a.x; v[1] = (f16)a.y; v[2] = (f16)a.z; v[3] = (f16)a.w;
    v[4] = (f16)b.x; v[5] = (f16)b.y; v[6] = (f16)b.z; v[7] = (f16)b.w;
    *(f16x8*)(dst + off) = v;
    ss = fmaf(a.x, a.x, ss); ss = fmaf(a.y, a.y, ss);
    ss = fmaf(a.z, a.z, ss); ss = fmaf(a.w, a.w, ss);
    ss = fmaf(b.x, b.x, ss); ss = fmaf(b.y, b.y, ss);
    ss = fmaf(b.z, b.z, ss); ss = fmaf(b.w, b.w, ss);
  }
#pragma unroll
  for (int s = 1; s < 64; s <<= 1) ss += __shfl_xor(ss, s);
  if (lane == 0) norms[i] = sqrtf(ss);
}

// ---------------------------------------------------------------------------
// fp16 MFMA GEMM, split-K=2, f16 partials, BK=64. 128x128 tile, 256 thr =
// 4 waves (2x2), wave = 64x64 = 2x2 MFMA 32x32x16, 4 k-steps per BK iter
// (16 iters at Ks=1024). LDS 32 KB single buffer. Interior verbatim round-3.
//
// Round-8 change: L2-FIT XCD MAPPING. Round-6 PMC (43 us, all pipes <20%,
// FETCH 29.5 MB) + occupancy/dbuf nulls (R6,R7) => L3-refetch bound. Old
// mapping put ALL 8 ty panels on every XCD: working set B 4.2 MB + A 2.6 MB
// = 6.8 MB > 4 MB L2 -> every B-tile refetched from L3 (~330 MB, ~40 us).
// New decode: xcd = (kz<<2)|tylo, tx = slot>>1, ty = ((slot&1)<<2)|tylo.
// Per XCD: B-slice = 2 ty-panels x 1 kz-half = 512 KB (L2-resident, fetched
// once); A-tiles stream, consecutive slots share tx (back-to-back reuse).
// Per-XCD L3 traffic ~4x lower. Bijective over the same grid -> output
// bitwise-identical to round 3.
// Swizzle: physical chunk p = g ^ (row&7) -> conflict-free ds_read_b128.
// C/D 32x32 layout: col = lane&31, row = (reg&3) + 8*(reg>>2) + 4*(lane>>5).
// ---------------------------------------------------------------------------
#define TM 128
#define TN 128
#define BK 64

__global__ __launch_bounds__(256) void gemm_f16(const f16* __restrict__ A,
                                                const f16* __restrict__ B,
                                                f16* __restrict__ P,
                                                int K, int Ks, long partStride,
                                                int ldc) {
  __shared__ __align__(16) f16 As[TM * BK];  // 16 KB
  __shared__ __align__(16) f16 Bs[TN * BK];  // 16 KB

  const int l = blockIdx.x;
  const int xcd = l & 7;           // = (kz<<2) | tylo
  const int tylo = xcd & 3;
  const int kz = xcd >> 2;         // 0..1
  const int slot = l >> 3;
  const int tx = slot >> 1;
  const int ty = ((slot & 1) << 2) | tylo;   // 0..7
  const int row0 = tx * TM;
  const int col0 = ty * TN;
  const int kbase = kz * Ks;

  const int tid = threadIdx.x;
  const int wave = tid >> 6;
  const int lane = tid & 63;
  const int lr32 = lane & 31;    // row within 32-block (A) / col (B, C/D)
  const int half = lane >> 5;    // k-chunk half selector
  const int wr = (wave >> 1) * 64;
  const int wc = (wave & 1) * 64;

  // staging: 1024 16B-chunks per tile -> 4 instr/thread for A, 4 for B.
  // chunk id i = (row<<3)|p; source global chunk g = p ^ (row&7).
  const f16* ag[4];
  const f16* bg[4];
  f16* al[4];
  f16* bl[4];
#pragma unroll
  for (int s = 0; s < 4; s++) {
    const int i = (wave * 4 + s) * 64 + lane;   // == LDS chunk id (staging contract)
    const int row = i >> 3;
    const int cg = (i & 7) ^ (row & 7);
    ag[s] = A + (size_t)(row0 + row) * K + kbase + cg * 8;
    bg[s] = B + (size_t)(col0 + row) * K + kbase + cg * 8;
    al[s] = As + (wave * 4 + s) * 512;
    bl[s] = Bs + (wave * 4 + s) * 512;
  }

  // fragment offsets: for k-step s (K=16), lane reads global chunk
  // (s*2 + half) of row r at physical chunk ((s*2+half) ^ (r&7)).
  int aoff[2][4], boff[2][4];
#pragma unroll
  for (int b = 0; b < 2; b++) {
#pragma unroll
    for (int s = 0; s < 4; s++) {
      const int ra = wr + b * 32 + lr32;
      aoff[b][s] = ra * 64 + (((s * 2 + half) ^ (ra & 7)) << 3);
      const int rb = wc + b * 32 + lr32;
      boff[b][s] = rb * 64 + (((s * 2 + half) ^ (rb & 7)) << 3);
    }
  }

  f32x16 acc[2][2];
#pragma unroll
  for (int i = 0; i < 2; i++)
#pragma unroll
    for (int j = 0; j < 2; j++)
#pragma unroll
      for (int r = 0; r < 16; r++) acc[i][j][r] = 0.f;

  for (int k0 = 0; k0 < Ks; k0 += BK) {
#pragma unroll
    for (int s = 0; s < 4; s++) {
      async_ld16(ag[s] + k0, al[s]);
      async_ld16(bg[s] + k0, bl[s]);
    }
    __syncthreads();

#pragma unroll
    for (int s = 0; s < 4; s++) {
      f16x8 af[2], bf[2];
      af[0] = *(const f16x8*)(As + aoff[0][s]);
      af[1] = *(const f16x8*)(As + aoff[1][s]);
      bf[0] = *(const f16x8*)(Bs + boff[0][s]);
      bf[1] = *(const f16x8*)(Bs + boff[1][s]);
      acc[0][0] = __builtin_amdgcn_mfma_f32_32x32x16_f16(af[0], bf[0], acc[0][0], 0, 0, 0);
      acc[0][1] = __builtin_amdgcn_mfma_f32_32x32x16_f16(af[0], bf[1], acc[0][1], 0, 0, 0);
      acc[1][0] = __builtin_amdgcn_mfma_f32_32x32x16_f16(af[1], bf[0], acc[1][0], 0, 0, 0);
      acc[1][1] = __builtin_amdgcn_mfma_f32_32x32x16_f16(af[1], bf[1], acc[1][1], 0, 0, 0);
    }
    __syncthreads();
  }

  f16* out = P + (size_t)kz * partStride;
#pragma unroll
  for (int bi = 0; bi < 2; bi++)
#pragma unroll
    for (int reg = 0; reg < 16; reg++) {
      const int r = row0 + wr + bi * 32 + (reg & 3) + ((reg >> 2) << 3) + (half << 2);
#pragma unroll
      for (int bj = 0; bj < 2; bj++) {
        const int c = col0 + wc + bj * 32 + lr32;
        out[(size_t)r * ldc + c] = (f16)acc[bi][bj][reg];
      }
    }
}

// ---------------------------------------------------------------------------
// row_stats_fast: ONE WAVE per row, zero barriers. Lane owns 16 cols
// (lane*8..+7 and 512+lane*8..+7), coalesced f16x8 loads of both partials.
// Top-2/argmax + entropy via shfl_xor butterflies. Ambiguous rows go to a
// repair list; others bucket into per-class lists.
// ---------------------------------------------------------------------------
__global__ __launch_bounds__(256) void row_stats_fast(
    const f16* __restrict__ P, long partStride, int ldp, int Cc, int Nsup,
    float* __restrict__ ent, int* __restrict__ repCnt, int* __restrict__ repRows,
    int* __restrict__ cls_cnt, int* __restrict__ cls_idx) {
  const int wave = threadIdx.x >> 6;
  const int lane = threadIdx.x & 63;
  const int r = blockIdx.x * 4 + wave;
  if (r >= Nsup) return;

  const f16* base = P + (size_t)r * ldp + lane * 8;
  const f16x8 p0 = *(const f16x8*)(base);
  const f16x8 p1 = *(const f16x8*)(base + 512);
  const f16x8 q0 = *(const f16x8*)(base + partStride);
  const f16x8 q1 = *(const f16x8*)(base + partStride + 512);

  float v[16];
#pragma unroll
  for (int k = 0; k < 8; k++) v[k] = (float)p0[k] + (float)q0[k];
#pragma unroll
  for (int k = 0; k < 8; k++) v[8 + k] = (float)p1[k] + (float)q1[k];

  const int cbase = lane * 8;
#pragma unroll
  for (int k = 0; k < 16; k++) {
    const int col = (k < 8) ? (cbase + k) : (512 + cbase + k - 8);
    if (col >= Cc) v[k] = -3.0e38f;
  }

  // per-lane top-2 (+ lowest argmax idx; ascending col order within lane)
  float m1 = -3.0e38f, m2 = -3.0e38f;
  int i1 = 0x7fffffff;
#pragma unroll
  for (int k = 0; k < 16; k++) {
    const int col = (k < 8) ? (cbase + k) : (512 + cbase + k - 8);
    const float x = v[k];
    if (x > m1) { m2 = m1; m1 = x; i1 = col; }
    else if (x > m2) { m2 = x; }   // x==m1 lands here -> m2=m1 (gap 0)
  }
  // butterfly merge: all lanes converge to global (m1, m2, lowest i1)
#pragma unroll
  for (int s = 1; s < 64; s <<= 1) {
    const float om1 = __shfl_xor(m1, s);
    const float om2 = __shfl_xor(m2, s);
    const int oi1 = __shfl_xor(i1, s);
    if (om1 > m1) { m2 = fmaxf(m1, om2); m1 = om1; i1 = oi1; }
    else if (om1 < m1) { m2 = fmaxf(m2, om1); }
    else { i1 = min(i1, oi1); m2 = m1; }
  }

  // entropy rel. m1 (consumed only if a class exceeds K members)
  float s1 = 0.f, s2 = 0.f;
#pragma unroll
  for (int k = 0; k < 16; k++) {
    const int col = (k < 8) ? (cbase + k) : (512 + cbase + k - 8);
    if (col < Cc) {
      const float d = v[k] - m1;
      const float e = __expf(d);
      s1 += e;
      s2 = fmaf(d, e, s2);
    }
  }
#pragma unroll
  for (int s = 1; s < 64; s <<= 1) {
    s1 += __shfl_xor(s1, s);
    s2 += __shfl_xor(s2, s);
  }

  if (lane == 0) {
    ent[r] = logf(s1) - s2 / s1;
    if (m1 - m2 <= 2.0f * GAP_TAU) {
      const int p = atomicAdd(repCnt, 1);
      if (p < Nsup) repRows[p] = r;
    } else {
      const int p = atomicAdd(&cls_cnt[i1], 1);
      if (p < MAXLIST) cls_idx[(size_t)i1 * MAXLIST + p] = r;
    }
  }
}

// ---------------------------------------------------------------------------
// repair: one block per ambiguous row (strided over runtime count). Recomputes
// M1/M2 (exact comparisons -> same values as fast path), then the VERBATIM old
// candidate collection + exact fp32 block-dot code -> yhat unchanged.
// Buckets the resolved class.
// ---------------------------------------------------------------------------
__global__ __launch_bounds__(256) void repair_kernel(
    const f16* __restrict__ P, long partStride, int ldp, int Cc,
    const float* __restrict__ z, const float* __restrict__ W,
    const int* __restrict__ repCnt, const int* __restrict__ repRows,
    int* __restrict__ cls_cnt, int* __restrict__ cls_idx) {
  const int t = threadIdx.x;
  const int wave = t >> 6;
  const int lane = t & 63;
  __shared__ float sm1[4], sm2[4];
  __shared__ float bc[2];
  __shared__ int cand[64];
  __shared__ int ncand;
  __shared__ float red[256];
  const int nrep = *repCnt;

  for (int q = blockIdx.x; q < nrep; q += gridDim.x) {
    const int r = repRows[q];
    const int c0 = t * 4;
    float v[4] = {0.f, 0.f, 0.f, 0.f};
#pragma unroll
    for (int kz = 0; kz < SPLITK; kz++) {
      const f16x4 p = *(const f16x4*)(P + (size_t)kz * partStride + (size_t)r * ldp + c0);
#pragma unroll
      for (int k = 0; k < 4; k++) v[k] += (float)p[k];
    }
#pragma unroll
    for (int k = 0; k < 4; k++)
      if (c0 + k >= Cc) v[k] = -3.0e38f;

    // top-2 values only (indices resolved by exact dots below)
    float m1 = -3.0e38f, m2 = -3.0e38f;
#pragma unroll
    for (int k = 0; k < 4; k++) {
      const float x = v[k];
      if (x > m1) { m2 = m1; m1 = x; }
      else if (x > m2) { m2 = x; }
    }
#pragma unroll
    for (int s = 1; s < 64; s <<= 1) {
      const float om1 = __shfl_xor(m1, s);
      const float om2 = __shfl_xor(m2, s);
      if (om1 > m1) { m2 = fmaxf(m1, om2); m1 = om1; }
      else if (om1 < m1) { m2 = fmaxf(m2, om1); }
      else { m2 = m1; }
    }
    if (lane == 0) { sm1[wave] = m1; sm2[wave] = m2; }
    __syncthreads();
    if (t == 0) {
      float M1 = sm1[0], M2 = sm2[0];
#pragma unroll
      for (int w = 1; w < 4; w++) {
        const float o1 = sm1[w], o2 = sm2[w];
        if (o1 > M1) { M2 = fmaxf(M1, o2); M1 = o1; }
        else if (o1 < M1) { M2 = fmaxf(M2, o1); }
        else { M2 = M1; }
      }
      bc[0] = M1; bc[1] = M2;
      ncand = 0;
    }
    __syncthreads();
    const float M1 = bc[0];
    const float thresh = M1 - 2.0f * GAP_TAU;
#pragma unroll
    for (int k = 0; k < 4; k++) {
      if (c0 + k < Cc && v[k] >= thresh) {
        const int p = atomicAdd(&ncand, 1);
        if (p < 64) cand[p] = c0 + k;
      }
    }
    __syncthreads();
    const bool overflow = (ncand > 64);
    const int nc = overflow ? Cc : ncand;
    const float* srow = support_row(r, W, z, Cc);
    float best = -3.0e38f;
    int bi = 0x7fffffff;
    for (int j = 0; j < nc; j++) {
      const int c = overflow ? j : cand[j];
      const float* wrow = W + (size_t)c * D_DIM;
      float s = 0.f;
      for (int d = t; d < D_DIM; d += 256) s = fmaf(srow[d], wrow[d], s);
      red[t] = s;
      __syncthreads();
      for (int k = 128; k > 0; k >>= 1) {
        if (t < k) red[t] += red[t + k];
        __syncthreads();
      }
      const float val = red[0];
      __syncthreads();
      if (val > best || (val == best && c < bi)) { best = val; bi = c; }
    }
    if (t == 0) {
      const int p = atomicAdd(&cls_cnt[bi], 1);
      if (p < MAXLIST) cls_idx[(size_t)bi * MAXLIST + p] = r;
    }
    __syncthreads();   // shared reuse across q iterations
  }
}

// ---------------------------------------------------------------------------
// accum: per class — read pre-bucketed member list, top-K by entropy if
// count > K (never in practice: mean ~5, K=100), sum normalized rows,
// column-normalize, write f16 weights row. Pad classes write zeros.
// ---------------------------------------------------------------------------
__global__ __launch_bounds__(256) void accum_kernel(
    const float* __restrict__ z, const float* __restrict__ W,
    int C, int Nsup,
    const int* __restrict__ cls_cnt, const int* __restrict__ cls_idx,
    const float* __restrict__ ent, const float* __restrict__ norms,
    const int* __restrict__ Kp, f16* __restrict__ wh) {
  const int c = blockIdx.x;
  const int t = threadIdx.x;
  f16* dst = wh + (size_t)c * D_DIM + t * 8;
  if (c >= C) {
    f16x8 zz = {0, 0, 0, 0, 0, 0, 0, 0};
    *(f16x8*)dst = zz;
    return;
  }

  __shared__ int slist[MAXLIST];
  __shared__ unsigned char sel[MAXLIST];
  __shared__ float red[256];
  const int cnt = cls_cnt[c];
  const int n = min(cnt, MAXLIST);
  const int* list = cls_idx + (size_t)c * MAXLIST;
  for (int j = t; j < n; j += 256) slist[j] = list[j];
  __syncthreads();
  const int K = *Kp;
  const bool all = (cnt <= K);
  if (!all) {
    for (int j = t; j < n; j += 256) {
      const int si = slist[j];
      const float ei = ent[si];
      int rank = 0;
      for (int l = 0; l < n; l++) {
        const int sl = slist[l];
        const float el = ent[sl];
        rank += (el < ei || (el == ei && sl < si)) ? 1 : 0;
      }
      sel[j] = (rank < K) ? 1 : 0;
    }
    __syncthreads();
  }

  float a[8];
#pragma unroll
  for (int q = 0; q < 8; q++) a[q] = 0.f;
  for (int j = 0; j < n; j++) {
    if (!all && !sel[j]) continue;
    const int si = slist[j];
    const float* row = support_row(si, W, z, C) + t * 8;
    const float inv = 1.0f / fmaxf(norms[si], 1e-12f);
    const float4 p0 = *(const float4*)row;
    const float4 p1 = *(const float4*)(row + 4);
    a[0] = fmaf(p0.x, inv, a[0]); a[1] = fmaf(p0.y, inv, a[1]);
    a[2] = fmaf(p0.z, inv, a[2]); a[3] = fmaf(p0.w, inv, a[3]);
    a[4] = fmaf(p1.x, inv, a[4]); a[5] = fmaf(p1.y, inv, a[5]);
    a[6] = fmaf(p1.z, inv, a[6]); a[7] = fmaf(p1.w, inv, a[7]);
  }

  float ss = 0.f;
#pragma unroll
  for (int q = 0; q < 8; q++) ss = fmaf(a[q], a[q], ss);
  red[t] = ss;
  __syncthreads();
  for (int k = 128; k > 0; k >>= 1) {
    if (t < k) red[t] += red[t + k];
    __syncthreads();
  }
  const float invn = 1.0f / fmaxf(sqrtf(red[0]), 1e-12f);
  f16x8 o;
#pragma unroll
  for (int q = 0; q < 8; q++) o[q] = (f16)(a[q] * invn);
  *(f16x8*)dst = o;
}

// ---------------------------------------------------------------------------
// reduce_out: out[r][c] = sum of 2 f16 partials, c < Ncols. Two rows per
// block; thread owns 8 cols (f16x8 loads, 2x float4 store).
// ---------------------------------------------------------------------------
__global__ __launch_bounds__(256) void reduce_out(const f16* __restrict__ Q,
                                                  long partStride, int ldq,
                                                  float* __restrict__ out, int Ncols) {
  const int r = blockIdx.x * 2 + (threadIdx.x >> 7);
  const int c0 = (threadIdx.x & 127) * 8;
  const f16* base = Q + (size_t)r * ldq + c0;
  const f16x8 p = *(const f16x8*)(base);
  const f16x8 q = *(const f16x8*)(base + partStride);
  float v[8];
#pragma unroll
  for (int k = 0; k < 8; k++) v[k] = (float)p[k] + (float)q[k];
  float* o = out + (size_t)r * Ncols + c0;
  if (c0 + 8 <= Ncols) {
    *(float4*)(o) = make_float4(v[0], v[1], v[2], v[3]);
    *(float4*)(o + 4) = make_float4(v[4], v[5], v[6], v[7]);
  } else {
#pragma unroll
    for (int k = 0; k < 8; k++)
      if (c0 + k < Ncols) o[k] = v[k];
  }
}

// ---------------------------------------------------------------------------
// Launch
// ---------------------------------------------------------------------------
extern "C" void kernel_launch(void* const* d_in, const int* in_sizes, int n_in,
                              void* d_out, int out_size, void* d_ws, size_t ws_size,
                              hipStream_t stream) {
  const float* z = (const float*)d_in[0];
  const float* W = (const float*)d_in[1];
  const int* Kp = (const int*)d_in[2];

  const int D = D_DIM;
  const int B = in_sizes[0] / D;   // 4096
  const int C = in_sizes[1] / D;   // 1000
  const int Nsup = C + B;          // 5096
  const int Mpad = (Nsup + TM - 1) / TM * TM;  // 5120
  const int Npad = (C + TN - 1) / TN * TN;     // 1024

  char* ws = (char*)d_ws;
  size_t off = 0;
  auto alloc = [&](size_t bytes) -> void* {
    void* p = ws + off;
    off += (bytes + 255) & ~(size_t)255;
    return p;
  };

  const long pStride1 = (long)Mpad * Npad;   // f16 elems per partial (gemm1)
  const long pStride2 = (long)B * Npad;      // f16 elems per partial (gemm2)

  f16*   suph   = (f16*)alloc((size_t)Mpad * D * sizeof(f16));            // ~21.0 MB
  f16*   wh     = (f16*)alloc((size_t)Npad * D * sizeof(f16));            // ~4.2 MB
  f16*   P      = (f16*)alloc((size_t)SPLITK * pStride1 * sizeof(f16));   // ~21.0 MB
  float* ent    = (float*)alloc((size_t)Nsup * sizeof(float));
  float* norms  = (float*)alloc((size_t)Nsup * sizeof(float));
  int*   cls_cnt = (int*)alloc((size_t)C * sizeof(int));
  int*   cls_idx = (int*)alloc((size_t)C * MAXLIST * sizeof(int));        // ~4.1 MB
  int*   repCnt = (int*)alloc(sizeof(int));
  int*   repRows = (int*)alloc((size_t)Nsup * sizeof(int));
  f16*   Q      = P;  // reuse: P fully consumed by row_stats/repair before gemm2
  (void)ws_size;

  // 1) f16 support matrix (padded) + norms; zero class/repair counters
  prep_kernel<<<Mpad / 4, 256, 0, stream>>>(z, W, C, Nsup, suph, norms, cls_cnt, repCnt);

  // 2) logit partials: P[kz] = f16(supports @ W^T over K-half kz)
  //    grid 640 = 8 xcd * 80 slots; xcd = (kz<<2)|tylo -> per-XCD B-slice
  //    512 KB (L2-fit); slot = (tx<<1)|tyhi -> back-to-back A-tile reuse
  gemm_f16<<<640, 256, 0, stream>>>(suph, suph, P, D, D / SPLITK, pStride1, Npad);

  // 3) wave-per-row split-K merge + argmax/entropy; ambiguous -> repair list,
  //    resolved -> class buckets
  row_stats_fast<<<(Nsup + 3) / 4, 256, 0, stream>>>(P, pStride1, Npad, C, Nsup,
                                                     ent, repCnt, repRows,
                                                     cls_cnt, cls_idx);

  // 4) exact fp32 repair of ambiguous rows (dot order bitwise == round-3)
  repair_kernel<<<1024, 256, 0, stream>>>(P, pStride1, Npad, C, z, W,
                                          repCnt, repRows, cls_cnt, cls_idx);

  // 5) per-class gather/select/accumulate/normalize -> wh[Npad, D] f16
  accum_kernel<<<Npad, 256, 0, stream>>>(z, W, C, Nsup, cls_cnt, cls_idx,
                                         ent, norms, Kp, wh);

  // 6) output partials: Q[kz] = f16(z @ weights^T over K-half kz)
  //    grid 512 = 8 xcd * 64 slots (tx 0..31)
  gemm_f16<<<512, 256, 0, stream>>>(suph + (size_t)C * D, wh, Q, D, D / SPLITK,
                                    pStride2, Npad);

  // 7) out = sum of 2 f16 partials (valid C cols only)
  reduce_out<<<B / 2, 256, 0, stream>>>(Q, pStride2, Npad, (float*)d_out, C);
}

// Round 9
// 175.723 us; speedup vs baseline: 1.0955x; 1.0213x over previous
//
#include <hip/hip_runtime.h>
#include <math.h>

// Problem shape (from reference setup_inputs): B=4096, D=2048, C=1000, N=C+B=5096.
#define D_DIM 2048
// |approx_logit - exact_logit| bound: fp16-MFMA dot (~0.013) + 2x f16 partial
// roundings (~0.004). Candidate containment needs GAP_TAU >= true bound.
#define GAP_TAU 0.03f
#define SPLITK 2
#define MAXLIST 1024

typedef _Float16 f16;
typedef f16 f16x8 __attribute__((ext_vector_type(8)));
typedef f16 f16x4 __attribute__((ext_vector_type(4)));
typedef float f32x4 __attribute__((ext_vector_type(4)));
typedef float f32x16 __attribute__((ext_vector_type(16)));

__device__ __forceinline__ const float* support_row(int i, const float* __restrict__ W,
                                                    const float* __restrict__ z, int C) {
  return (i < C) ? (W + (size_t)i * D_DIM) : (z + (size_t)(i - C) * D_DIM);
}

// async global->LDS, 16B per lane. LDS dest = wave-uniform base + lane*16.
__device__ __forceinline__ void async_ld16(const f16* g, f16* l) {
  __builtin_amdgcn_global_load_lds((const __attribute__((address_space(1))) void*)g,
                                   (__attribute__((address_space(3))) void*)l, 16, 0, 0);
}

// ---------------------------------------------------------------------------
// prep: suph[i][:] = f16(support_row(i)) (zeros for pad rows); norms[i] = ||row||.
// One wave per row (4 rows/block), shuffle-only reduction.
// Also zeroes cls_cnt[0..C) and *repCnt (consumed after row_stats_fast).
// ---------------------------------------------------------------------------
__global__ __launch_bounds__(256) void prep_kernel(const float* __restrict__ z,
                                                   const float* __restrict__ W,
                                                   int C, int Nsup,
                                                   f16* __restrict__ suph,
                                                   float* __restrict__ norms,
                                                   int* __restrict__ cls_cnt,
                                                   int* __restrict__ repCnt) {
  if (blockIdx.x * 256 <= (unsigned)C) {
    const int gi = blockIdx.x * 256 + threadIdx.x;
    if (gi < C) cls_cnt[gi] = 0;
    if (gi == C) *repCnt = 0;
  }
  const int wave = threadIdx.x >> 6;
  const int lane = threadIdx.x & 63;
  const int i = blockIdx.x * 4 + wave;
  f16* dst = suph + (size_t)i * D_DIM;
  if (i >= Nsup) {
    f16x8 zz = {0, 0, 0, 0, 0, 0, 0, 0};
#pragma unroll
    for (int p = 0; p < 4; p++) *(f16x8*)(dst + p * 512 + lane * 8) = zz;
    return;
  }
  const float* src = support_row(i, W, z, C);
  float ss = 0.f;
#pragma unroll
  for (int p = 0; p < 4; p++) {
    const int off = p * 512 + lane * 8;
    const float4 a = *(const float4*)(src + off);
    const float4 b = *(const float4*)(src + off + 4);
    f16x8 v;
    v[0] = (f16)a.x; v[1] = (f16)a.y; v[2] = (f16)a.z; v[3] = (f16)a.w;
    v[4] = (f16)b.x; v[5] = (f16)b.y; v[6] = (f16)b.z; v[7] = (f16)b.w;
    *(f16x8*)(dst + off) = v;
    ss = fmaf(a.x, a.x, ss); ss = fmaf(a.y, a.y, ss);
    ss = fmaf(a.z, a.z, ss); ss = fmaf(a.w, a.w, ss);
    ss = fmaf(b.x, b.x, ss); ss = fmaf(b.y, b.y, ss);
    ss = fmaf(b.z, b.z, ss); ss = fmaf(b.w, b.w, ss);
  }
#pragma unroll
  for (int s = 1; s < 64; s <<= 1) ss += __shfl_xor(ss, s);
  if (lane == 0) norms[i] = sqrtf(ss);
}

// ---------------------------------------------------------------------------
// gemm1: fp16 MFMA, split-K=2, f16 partials, BK=64. 128x128 tile, 4 waves,
// wave = 64x64 = 2x2 MFMA 32x32x16, 4 k-steps per BK iter (16 iters, Ks=1024).
// LDS 32 KB single buffer. R8 L2-fit XCD map: xcd = (kz<<2)|tylo -> per-XCD
// B-slice 512 KB L2-resident; slot = (tx<<1)|tyhi.
// Swizzle: physical chunk p = g ^ (row&7) -> conflict-free ds_read_b128.
// C/D 32x32 layout: col = lane&31, row = (reg&3) + 8*(reg>>2) + 4*(lane>>5).
// ---------------------------------------------------------------------------
#define TM 128
#define TN 128
#define BK 64

__global__ __launch_bounds__(256) void gemm_f16(const f16* __restrict__ A,
                                                const f16* __restrict__ B,
                                                f16* __restrict__ P,
                                                int K, int Ks, long partStride,
                                                int ldc) {
  __shared__ __align__(16) f16 As[TM * BK];  // 16 KB
  __shared__ __align__(16) f16 Bs[TN * BK];  // 16 KB

  const int l = blockIdx.x;
  const int xcd = l & 7;           // = (kz<<2) | tylo
  const int tylo = xcd & 3;
  const int kz = xcd >> 2;         // 0..1
  const int slot = l >> 3;
  const int tx = slot >> 1;
  const int ty = ((slot & 1) << 2) | tylo;   // 0..7
  const int row0 = tx * TM;
  const int col0 = ty * TN;
  const int kbase = kz * Ks;

  const int tid = threadIdx.x;
  const int wave = tid >> 6;
  const int lane = tid & 63;
  const int lr32 = lane & 31;    // row within 32-block (A) / col (B, C/D)
  const int half = lane >> 5;    // k-chunk half selector
  const int wr = (wave >> 1) * 64;
  const int wc = (wave & 1) * 64;

  // staging: 1024 16B-chunks per tile -> 4 instr/thread for A, 4 for B.
  // chunk id i = (row<<3)|p; source global chunk g = p ^ (row&7).
  const f16* ag[4];
  const f16* bg[4];
  f16* al[4];
  f16* bl[4];
#pragma unroll
  for (int s = 0; s < 4; s++) {
    const int i = (wave * 4 + s) * 64 + lane;   // == LDS chunk id (staging contract)
    const int row = i >> 3;
    const int cg = (i & 7) ^ (row & 7);
    ag[s] = A + (size_t)(row0 + row) * K + kbase + cg * 8;
    bg[s] = B + (size_t)(col0 + row) * K + kbase + cg * 8;
    al[s] = As + (wave * 4 + s) * 512;
    bl[s] = Bs + (wave * 4 + s) * 512;
  }

  // fragment offsets: for k-step s (K=16), lane reads global chunk
  // (s*2 + half) of row r at physical chunk ((s*2+half) ^ (r&7)).
  int aoff[2][4], boff[2][4];
#pragma unroll
  for (int b = 0; b < 2; b++) {
#pragma unroll
    for (int s = 0; s < 4; s++) {
      const int ra = wr + b * 32 + lr32;
      aoff[b][s] = ra * 64 + (((s * 2 + half) ^ (ra & 7)) << 3);
      const int rb = wc + b * 32 + lr32;
      boff[b][s] = rb * 64 + (((s * 2 + half) ^ (rb & 7)) << 3);
    }
  }

  f32x16 acc[2][2];
#pragma unroll
  for (int i = 0; i < 2; i++)
#pragma unroll
    for (int j = 0; j < 2; j++)
#pragma unroll
      for (int r = 0; r < 16; r++) acc[i][j][r] = 0.f;

  for (int k0 = 0; k0 < Ks; k0 += BK) {
#pragma unroll
    for (int s = 0; s < 4; s++) {
      async_ld16(ag[s] + k0, al[s]);
      async_ld16(bg[s] + k0, bl[s]);
    }
    __syncthreads();

#pragma unroll
    for (int s = 0; s < 4; s++) {
      f16x8 af[2], bf[2];
      af[0] = *(const f16x8*)(As + aoff[0][s]);
      af[1] = *(const f16x8*)(As + aoff[1][s]);
      bf[0] = *(const f16x8*)(Bs + boff[0][s]);
      bf[1] = *(const f16x8*)(Bs + boff[1][s]);
      acc[0][0] = __builtin_amdgcn_mfma_f32_32x32x16_f16(af[0], bf[0], acc[0][0], 0, 0, 0);
      acc[0][1] = __builtin_amdgcn_mfma_f32_32x32x16_f16(af[0], bf[1], acc[0][1], 0, 0, 0);
      acc[1][0] = __builtin_amdgcn_mfma_f32_32x32x16_f16(af[1], bf[0], acc[1][0], 0, 0, 0);
      acc[1][1] = __builtin_amdgcn_mfma_f32_32x32x16_f16(af[1], bf[1], acc[1][1], 0, 0, 0);
    }
    __syncthreads();
  }

  f16* out = P + (size_t)kz * partStride;
#pragma unroll
  for (int bi = 0; bi < 2; bi++)
#pragma unroll
    for (int reg = 0; reg < 16; reg++) {
      const int r = row0 + wr + bi * 32 + (reg & 3) + ((reg >> 2) << 3) + (half << 2);
#pragma unroll
      for (int bj = 0; bj < 2; bj++) {
        const int c = col0 + wc + bj * 32 + lr32;
        out[(size_t)r * ldc + c] = (f16)acc[bi][bj][reg];
      }
    }
}

// ---------------------------------------------------------------------------
// gemm2_out: fp16 MFMA, SPLIT-K=1 (Ks = K = 2048, 32 iters), f32 output
// written DIRECTLY to d_out (cols < Ncols) -> reduce_out kernel deleted.
// Round-9 rationale: same compute makespan as splitK=2 (256 blocks x 32
// iters = 1/CU zero-tail vs 512 x 16 = 2 passes), minus 33 MB partial
// traffic, minus one launch+gap. Interior = R6's proven double-buffered
// 2-phase loop (at 1 block/CU, intra-block stage/compute overlap is the
// only latency hiding available). XCD map: xcd = ty (one 512 KB wh-panel
// L2-resident per XCD), slot = tx. Output = full-K f32 accumulator (fewer
// roundings than the old f16-partial sum).
// ---------------------------------------------------------------------------
__global__ __launch_bounds__(256) void gemm2_out(const f16* __restrict__ A,
                                                 const f16* __restrict__ B,
                                                 float* __restrict__ out,
                                                 int K, int Ncols) {
  // buf k: As at k*16384, Bs at k*16384 + 8192 (f16 elems). 64 KB total.
  __shared__ __align__(16) f16 sh[2 * 16384];

  const int l = blockIdx.x;
  const int ty = l & 7;            // XCD id = ty -> B-panel pinned per XCD
  const int tx = l >> 3;           // 0..31
  const int row0 = tx * TM;
  const int col0 = ty * TN;

  const int tid = threadIdx.x;
  const int wave = tid >> 6;
  const int lane = tid & 63;
  const int lr32 = lane & 31;
  const int half = lane >> 5;
  const int wr = (wave >> 1) * 64;
  const int wc = (wave & 1) * 64;

  const f16* ag[4];
  const f16* bg[4];
  int aloff[4], bloff[4];
#pragma unroll
  for (int s = 0; s < 4; s++) {
    const int i = (wave * 4 + s) * 64 + lane;
    const int row = i >> 3;
    const int cg = (i & 7) ^ (row & 7);
    ag[s] = A + (size_t)(row0 + row) * K + cg * 8;
    bg[s] = B + (size_t)(col0 + row) * K + cg * 8;
    aloff[s] = (wave * 4 + s) * 512;          // within As of a buffer
    bloff[s] = 8192 + (wave * 4 + s) * 512;   // within Bs of a buffer
  }

  int aoff[2][4], boff[2][4];
#pragma unroll
  for (int b = 0; b < 2; b++) {
#pragma unroll
    for (int s = 0; s < 4; s++) {
      const int ra = wr + b * 32 + lr32;
      aoff[b][s] = ra * 64 + (((s * 2 + half) ^ (ra & 7)) << 3);
      const int rb = wc + b * 32 + lr32;
      boff[b][s] = 8192 + rb * 64 + (((s * 2 + half) ^ (rb & 7)) << 3);
    }
  }

  f32x16 acc[2][2];
#pragma unroll
  for (int i = 0; i < 2; i++)
#pragma unroll
    for (int j = 0; j < 2; j++)
#pragma unroll
      for (int r = 0; r < 16; r++) acc[i][j][r] = 0.f;

  const int NT = K / BK;   // 32

  // prologue: stage tile 0 into buf 0
#pragma unroll
  for (int s = 0; s < 4; s++) {
    async_ld16(ag[s], sh + aloff[s]);
    async_ld16(bg[s], sh + bloff[s]);
  }
  __syncthreads();

  int cur = 0;
#pragma unroll 1
  for (int t = 0; t < NT; ++t) {
    if (t + 1 < NT) {
      const int nb = (cur ^ 1) * 16384;
      const int ko = (t + 1) * BK;
#pragma unroll
      for (int s = 0; s < 4; s++) {
        async_ld16(ag[s] + ko, sh + nb + aloff[s]);
        async_ld16(bg[s] + ko, sh + nb + bloff[s]);
      }
    }

    const f16* buf = sh + cur * 16384;
#pragma unroll
    for (int s = 0; s < 2; s++) {
      f16x8 af[4], bf[4];
#pragma unroll
      for (int i = 0; i < 4; i++) af[i] = *(const f16x8*)(buf + aoff[i & 1][s * 2 + (i >> 1)]);
#pragma unroll
      for (int i = 0; i < 4; i++) bf[i] = *(const f16x8*)(buf + boff[i & 1][s * 2 + (i >> 1)]);
      acc[0][0] = __builtin_amdgcn_mfma_f32_32x32x16_f16(af[0], bf[0], acc[0][0], 0, 0, 0);
      acc[0][1] = __builtin_amdgcn_mfma_f32_32x32x16_f16(af[0], bf[1], acc[0][1], 0, 0, 0);
      acc[1][0] = __builtin_amdgcn_mfma_f32_32x32x16_f16(af[1], bf[0], acc[1][0], 0, 0, 0);
      acc[1][1] = __builtin_amdgcn_mfma_f32_32x32x16_f16(af[1], bf[1], acc[1][1], 0, 0, 0);
      acc[0][0] = __builtin_amdgcn_mfma_f32_32x32x16_f16(af[2], bf[2], acc[0][0], 0, 0, 0);
      acc[0][1] = __builtin_amdgcn_mfma_f32_32x32x16_f16(af[2], bf[3], acc[0][1], 0, 0, 0);
      acc[1][0] = __builtin_amdgcn_mfma_f32_32x32x16_f16(af[3], bf[2], acc[1][0], 0, 0, 0);
      acc[1][1] = __builtin_amdgcn_mfma_f32_32x32x16_f16(af[3], bf[3], acc[1][1], 0, 0, 0);
    }
    __syncthreads();   // drains own vmcnt (staged t+1 lands) + publishes buf free
    cur ^= 1;
  }

  // f32 epilogue straight to d_out; guard c < Ncols (=1000 < Npad tile cols)
#pragma unroll
  for (int bi = 0; bi < 2; bi++)
#pragma unroll
    for (int reg = 0; reg < 16; reg++) {
      const int r = row0 + wr + bi * 32 + (reg & 3) + ((reg >> 2) << 3) + (half << 2);
#pragma unroll
      for (int bj = 0; bj < 2; bj++) {
        const int c = col0 + wc + bj * 32 + lr32;
        if (c < Ncols) out[(size_t)r * Ncols + c] = acc[bi][bj][reg];
      }
    }
}

// ---------------------------------------------------------------------------
// row_stats_fast: ONE WAVE per row, zero barriers. Lane owns 16 cols
// (lane*8..+7 and 512+lane*8..+7), coalesced f16x8 loads of both partials.
// Top-2/argmax + entropy via shfl_xor butterflies. Ambiguous rows go to a
// repair list; others bucket into per-class lists.
// ---------------------------------------------------------------------------
__global__ __launch_bounds__(256) void row_stats_fast(
    const f16* __restrict__ P, long partStride, int ldp, int Cc, int Nsup,
    float* __restrict__ ent, int* __restrict__ repCnt, int* __restrict__ repRows,
    int* __restrict__ cls_cnt, int* __restrict__ cls_idx) {
  const int wave = threadIdx.x >> 6;
  const int lane = threadIdx.x & 63;
  const int r = blockIdx.x * 4 + wave;
  if (r >= Nsup) return;

  const f16* base = P + (size_t)r * ldp + lane * 8;
  const f16x8 p0 = *(const f16x8*)(base);
  const f16x8 p1 = *(const f16x8*)(base + 512);
  const f16x8 q0 = *(const f16x8*)(base + partStride);
  const f16x8 q1 = *(const f16x8*)(base + partStride + 512);

  float v[16];
#pragma unroll
  for (int k = 0; k < 8; k++) v[k] = (float)p0[k] + (float)q0[k];
#pragma unroll
  for (int k = 0; k < 8; k++) v[8 + k] = (float)p1[k] + (float)q1[k];

  const int cbase = lane * 8;
#pragma unroll
  for (int k = 0; k < 16; k++) {
    const int col = (k < 8) ? (cbase + k) : (512 + cbase + k - 8);
    if (col >= Cc) v[k] = -3.0e38f;
  }

  // per-lane top-2 (+ lowest argmax idx; ascending col order within lane)
  float m1 = -3.0e38f, m2 = -3.0e38f;
  int i1 = 0x7fffffff;
#pragma unroll
  for (int k = 0; k < 16; k++) {
    const int col = (k < 8) ? (cbase + k) : (512 + cbase + k - 8);
    const float x = v[k];
    if (x > m1) { m2 = m1; m1 = x; i1 = col; }
    else if (x > m2) { m2 = x; }   // x==m1 lands here -> m2=m1 (gap 0)
  }
  // butterfly merge: all lanes converge to global (m1, m2, lowest i1)
#pragma unroll
  for (int s = 1; s < 64; s <<= 1) {
    const float om1 = __shfl_xor(m1, s);
    const float om2 = __shfl_xor(m2, s);
    const int oi1 = __shfl_xor(i1, s);
    if (om1 > m1) { m2 = fmaxf(m1, om2); m1 = om1; i1 = oi1; }
    else if (om1 < m1) { m2 = fmaxf(m2, om1); }
    else { i1 = min(i1, oi1); m2 = m1; }
  }

  // entropy rel. m1 (consumed only if a class exceeds K members)
  float s1 = 0.f, s2 = 0.f;
#pragma unroll
  for (int k = 0; k < 16; k++) {
    const int col = (k < 8) ? (cbase + k) : (512 + cbase + k - 8);
    if (col < Cc) {
      const float d = v[k] - m1;
      const float e = __expf(d);
      s1 += e;
      s2 = fmaf(d, e, s2);
    }
  }
#pragma unroll
  for (int s = 1; s < 64; s <<= 1) {
    s1 += __shfl_xor(s1, s);
    s2 += __shfl_xor(s2, s);
  }

  if (lane == 0) {
    ent[r] = logf(s1) - s2 / s1;
    if (m1 - m2 <= 2.0f * GAP_TAU) {
      const int p = atomicAdd(repCnt, 1);
      if (p < Nsup) repRows[p] = r;
    } else {
      const int p = atomicAdd(&cls_cnt[i1], 1);
      if (p < MAXLIST) cls_idx[(size_t)i1 * MAXLIST + p] = r;
    }
  }
}

// ---------------------------------------------------------------------------
// repair: one block per ambiguous row (strided over runtime count). Recomputes
// M1/M2 (exact comparisons -> same values as fast path), then the VERBATIM old
// candidate collection + exact fp32 block-dot code -> yhat unchanged.
// Buckets the resolved class.
// ---------------------------------------------------------------------------
__global__ __launch_bounds__(256) void repair_kernel(
    const f16* __restrict__ P, long partStride, int ldp, int Cc,
    const float* __restrict__ z, const float* __restrict__ W,
    const int* __restrict__ repCnt, const int* __restrict__ repRows,
    int* __restrict__ cls_cnt, int* __restrict__ cls_idx) {
  const int t = threadIdx.x;
  const int wave = t >> 6;
  const int lane = t & 63;
  __shared__ float sm1[4], sm2[4];
  __shared__ float bc[2];
  __shared__ int cand[64];
  __shared__ int ncand;
  __shared__ float red[256];
  const int nrep = *repCnt;

  for (int q = blockIdx.x; q < nrep; q += gridDim.x) {
    const int r = repRows[q];
    const int c0 = t * 4;
    float v[4] = {0.f, 0.f, 0.f, 0.f};
#pragma unroll
    for (int kz = 0; kz < SPLITK; kz++) {
      const f16x4 p = *(const f16x4*)(P + (size_t)kz * partStride + (size_t)r * ldp + c0);
#pragma unroll
      for (int k = 0; k < 4; k++) v[k] += (float)p[k];
    }
#pragma unroll
    for (int k = 0; k < 4; k++)
      if (c0 + k >= Cc) v[k] = -3.0e38f;

    // top-2 values only (indices resolved by exact dots below)
    float m1 = -3.0e38f, m2 = -3.0e38f;
#pragma unroll
    for (int k = 0; k < 4; k++) {
      const float x = v[k];
      if (x > m1) { m2 = m1; m1 = x; }
      else if (x > m2) { m2 = x; }
    }
#pragma unroll
    for (int s = 1; s < 64; s <<= 1) {
      const float om1 = __shfl_xor(m1, s);
      const float om2 = __shfl_xor(m2, s);
      if (om1 > m1) { m2 = fmaxf(m1, om2); m1 = om1; }
      else if (om1 < m1) { m2 = fmaxf(m2, om1); }
      else { m2 = m1; }
    }
    if (lane == 0) { sm1[wave] = m1; sm2[wave] = m2; }
    __syncthreads();
    if (t == 0) {
      float M1 = sm1[0], M2 = sm2[0];
#pragma unroll
      for (int w = 1; w < 4; w++) {
        const float o1 = sm1[w], o2 = sm2[w];
        if (o1 > M1) { M2 = fmaxf(M1, o2); M1 = o1; }
        else if (o1 < M1) { M2 = fmaxf(M2, o1); }
        else { M2 = M1; }
      }
      bc[0] = M1; bc[1] = M2;
      ncand = 0;
    }
    __syncthreads();
    const float M1 = bc[0];
    const float thresh = M1 - 2.0f * GAP_TAU;
#pragma unroll
    for (int k = 0; k < 4; k++) {
      if (c0 + k < Cc && v[k] >= thresh) {
        const int p = atomicAdd(&ncand, 1);
        if (p < 64) cand[p] = c0 + k;
      }
    }
    __syncthreads();
    const bool overflow = (ncand > 64);
    const int nc = overflow ? Cc : ncand;
    const float* srow = support_row(r, W, z, Cc);
    float best = -3.0e38f;
    int bi = 0x7fffffff;
    for (int j = 0; j < nc; j++) {
      const int c = overflow ? j : cand[j];
      const float* wrow = W + (size_t)c * D_DIM;
      float s = 0.f;
      for (int d = t; d < D_DIM; d += 256) s = fmaf(srow[d], wrow[d], s);
      red[t] = s;
      __syncthreads();
      for (int k = 128; k > 0; k >>= 1) {
        if (t < k) red[t] += red[t + k];
        __syncthreads();
      }
      const float val = red[0];
      __syncthreads();
      if (val > best || (val == best && c < bi)) { best = val; bi = c; }
    }
    if (t == 0) {
      const int p = atomicAdd(&cls_cnt[bi], 1);
      if (p < MAXLIST) cls_idx[(size_t)bi * MAXLIST + p] = r;
    }
    __syncthreads();   // shared reuse across q iterations
  }
}

// ---------------------------------------------------------------------------
// accum: per class — read pre-bucketed member list, top-K by entropy if
// count > K (never in practice: mean ~5, K=100), sum normalized rows,
// column-normalize, write f16 weights row. Pad classes write zeros.
// ---------------------------------------------------------------------------
__global__ __launch_bounds__(256) void accum_kernel(
    const float* __restrict__ z, const float* __restrict__ W,
    int C, int Nsup,
    const int* __restrict__ cls_cnt, const int* __restrict__ cls_idx,
    const float* __restrict__ ent, const float* __restrict__ norms,
    const int* __restrict__ Kp, f16* __restrict__ wh) {
  const int c = blockIdx.x;
  const int t = threadIdx.x;
  f16* dst = wh + (size_t)c * D_DIM + t * 8;
  if (c >= C) {
    f16x8 zz = {0, 0, 0, 0, 0, 0, 0, 0};
    *(f16x8*)dst = zz;
    return;
  }

  __shared__ int slist[MAXLIST];
  __shared__ unsigned char sel[MAXLIST];
  __shared__ float red[256];
  const int cnt = cls_cnt[c];
  const int n = min(cnt, MAXLIST);
  const int* list = cls_idx + (size_t)c * MAXLIST;
  for (int j = t; j < n; j += 256) slist[j] = list[j];
  __syncthreads();
  const int K = *Kp;
  const bool all = (cnt <= K);
  if (!all) {
    for (int j = t; j < n; j += 256) {
      const int si = slist[j];
      const float ei = ent[si];
      int rank = 0;
      for (int l = 0; l < n; l++) {
        const int sl = slist[l];
        const float el = ent[sl];
        rank += (el < ei || (el == ei && sl < si)) ? 1 : 0;
      }
      sel[j] = (rank < K) ? 1 : 0;
    }
    __syncthreads();
  }

  float a[8];
#pragma unroll
  for (int q = 0; q < 8; q++) a[q] = 0.f;
  for (int j = 0; j < n; j++) {
    if (!all && !sel[j]) continue;
    const int si = slist[j];
    const float* row = support_row(si, W, z, C) + t * 8;
    const float inv = 1.0f / fmaxf(norms[si], 1e-12f);
    const float4 p0 = *(const float4*)row;
    const float4 p1 = *(const float4*)(row + 4);
    a[0] = fmaf(p0.x, inv, a[0]); a[1] = fmaf(p0.y, inv, a[1]);
    a[2] = fmaf(p0.z, inv, a[2]); a[3] = fmaf(p0.w, inv, a[3]);
    a[4] = fmaf(p1.x, inv, a[4]); a[5] = fmaf(p1.y, inv, a[5]);
    a[6] = fmaf(p1.z, inv, a[6]); a[7] = fmaf(p1.w, inv, a[7]);
  }

  float ss = 0.f;
#pragma unroll
  for (int q = 0; q < 8; q++) ss = fmaf(a[q], a[q], ss);
  red[t] = ss;
  __syncthreads();
  for (int k = 128; k > 0; k >>= 1) {
    if (t < k) red[t] += red[t + k];
    __syncthreads();
  }
  const float invn = 1.0f / fmaxf(sqrtf(red[0]), 1e-12f);
  f16x8 o;
#pragma unroll
  for (int q = 0; q < 8; q++) o[q] = (f16)(a[q] * invn);
  *(f16x8*)dst = o;
}

// ---------------------------------------------------------------------------
// Launch
// ---------------------------------------------------------------------------
extern "C" void kernel_launch(void* const* d_in, const int* in_sizes, int n_in,
                              void* d_out, int out_size, void* d_ws, size_t ws_size,
                              hipStream_t stream) {
  const float* z = (const float*)d_in[0];
  const float* W = (const float*)d_in[1];
  const int* Kp = (const int*)d_in[2];

  const int D = D_DIM;
  const int B = in_sizes[0] / D;   // 4096
  const int C = in_sizes[1] / D;   // 1000
  const int Nsup = C + B;          // 5096
  const int Mpad = (Nsup + TM - 1) / TM * TM;  // 5120
  const int Npad = (C + TN - 1) / TN * TN;     // 1024

  char* ws = (char*)d_ws;
  size_t off = 0;
  auto alloc = [&](size_t bytes) -> void* {
    void* p = ws + off;
    off += (bytes + 255) & ~(size_t)255;
    return p;
  };

  const long pStride1 = (long)Mpad * Npad;   // f16 elems per partial (gemm1)

  f16*   suph   = (f16*)alloc((size_t)Mpad * D * sizeof(f16));            // ~21.0 MB
  f16*   wh     = (f16*)alloc((size_t)Npad * D * sizeof(f16));            // ~4.2 MB
  f16*   P      = (f16*)alloc((size_t)SPLITK * pStride1 * sizeof(f16));   // ~21.0 MB
  float* ent    = (float*)alloc((size_t)Nsup * sizeof(float));
  float* norms  = (float*)alloc((size_t)Nsup * sizeof(float));
  int*   cls_cnt = (int*)alloc((size_t)C * sizeof(int));
  int*   cls_idx = (int*)alloc((size_t)C * MAXLIST * sizeof(int));        // ~4.1 MB
  int*   repCnt = (int*)alloc(sizeof(int));
  int*   repRows = (int*)alloc((size_t)Nsup * sizeof(int));
  (void)ws_size;

  // 1) f16 support matrix (padded) + norms; zero class/repair counters
  prep_kernel<<<Mpad / 4, 256, 0, stream>>>(z, W, C, Nsup, suph, norms, cls_cnt, repCnt);

  // 2) logit partials: P[kz] = f16(supports @ W^T over K-half kz)
  //    grid 640 = 8 xcd * 80 slots; xcd = (kz<<2)|tylo -> per-XCD B-slice
  //    512 KB (L2-fit); slot = (tx<<1)|tyhi -> back-to-back A-tile reuse
  gemm_f16<<<640, 256, 0, stream>>>(suph, suph, P, D, D / SPLITK, pStride1, Npad);

  // 3) wave-per-row split-K merge + argmax/entropy; ambiguous -> repair list,
  //    resolved -> class buckets
  row_stats_fast<<<(Nsup + 3) / 4, 256, 0, stream>>>(P, pStride1, Npad, C, Nsup,
                                                     ent, repCnt, repRows,
                                                     cls_cnt, cls_idx);

  // 4) exact fp32 repair of ambiguous rows (dot order bitwise == round-3)
  repair_kernel<<<1024, 256, 0, stream>>>(P, pStride1, Npad, C, z, W,
                                          repCnt, repRows, cls_cnt, cls_idx);

  // 5) per-class gather/select/accumulate/normalize -> wh[Npad, D] f16
  accum_kernel<<<Npad, 256, 0, stream>>>(z, W, C, Nsup, cls_cnt, cls_idx,
                                         ent, norms, Kp, wh);

  // 6) out = z @ weights^T, split-K=1, f32 epilogue straight to d_out.
  //    grid 256 = 8 xcd (=ty, B-panel L2-pinned) * 32 tx = exactly 1/CU.
  gemm2_out<<<256, 256, 0, stream>>>(suph + (size_t)C * D, wh, (float*)d_out,
                                     D, C);
}